// Round 12
// baseline (138.835 us; speedup 1.0000x reference)
//
#include <hip/hip_runtime.h>

// Path signature, depth 4: B=32, L=1024, d=8, fp32.
// Levels: S1(8) S2(64) S3(512) S4(4096); sig stride 4680 floats.
//
// R12: 2 dispatches, NO in-kernel grid barriers (R7/R11 proved each
// agent-scope barrier costs ~30us in L2 writeback/invalidate).
//  sig_chunk: R10 verbatim (measured best). One block per chunk, 4 k-slice
//    q-waves, 33 path rows staged in LDS.
//  sig_foldtree: 32 blocks x 512 threads, one block per batch. 5-round
//    binary-tree Chen reduction of the 32 chunk sigs INSIDE the block
//    (__syncthreads only; same CU -> L1/L2 coherent, no flushes):
//    levels 1-3 of all 32 sigs live in 74.7KB LDS; S4 read/written in the
//    block's XCD-local L2. Serial depth 6 folds (vs 10 in fold8+fold4).
//    Tree association == reference's binary tree.
// Lessons: (R2) never unroll fold loops blindly; (R3) reg headroom or loads
// serialize; (R7/R8) keep prefetch state modest or compiler sinks it; (R8)
// no +4 LDS padding; (R9/R10) harness floor ~53us; (R11) in-kernel grid
// barriers ~30us each -> kernel boundaries are the cheap barrier.

#define D 8
#define LPATH 1024
#define BATCH 32
#define CHUNKS 32
#define MSTEP 32
#define SIG_STRIDE 4680
#define OFF2 8
#define OFF3 72
#define OFF4 584
#define L13F 584            // floats of levels 1-3 per sig
#define L13F4 146           // float4s of levels 1-3 per sig

__device__ __forceinline__ void load8(const float* __restrict__ p, float* dst) {
  float4 lo = *(const float4*)p;
  float4 hi = *(const float4*)(p + 4);
  dst[0] = lo.x; dst[1] = lo.y; dst[2] = lo.z; dst[3] = lo.w;
  dst[4] = hi.x; dst[5] = hi.y; dst[6] = hi.z; dst[7] = hi.w;
}

__device__ __forceinline__ void store8(float* __restrict__ p, const float* src) {
  *(float4*)p       = make_float4(src[0], src[1], src[2], src[3]);
  *(float4*)(p + 4) = make_float4(src[4], src[5], src[6], src[7]);
}

// ------ Kernel 1: one block per chunk; path staged via LDS (R10 verbatim) ---
__global__ __launch_bounds__(256) void sig_chunk(const float* __restrict__ path,
                                                 float* __restrict__ ws) {
  __shared__ alignas(16) float lp[33 * D];  // 1.05 KB

  const int tid  = threadIdx.x;
  const int lane = tid & 63;
  const int q    = tid >> 6;               // k-slice wave 0..3
  const int b = blockIdx.x >> 5;           // batch
  const int c = blockIdx.x & (CHUNKS - 1); // chunk
  const int i = lane >> 3;
  const int j = lane & 7;
  const int k0 = q * 2;

  const int g0 = c * MSTEP;
  const int nrows = (33 < LPATH - g0) ? 33 : (LPATH - g0);
  const int nf4 = nrows * 2;
  const float* __restrict__ bp = path + (size_t)b * (LPATH * D) + (size_t)g0 * D;

  if (tid < nf4) *(float4*)&lp[4 * tid] = *(const float4*)(bp + 4 * tid);
  __syncthreads();

  float cm[D];
  *(float4*)&cm[0] = *(const float4*)&lp[0];
  *(float4*)&cm[4] = *(const float4*)&lp[4];
  float cwi = lp[i], cwj = lp[j];

  float s1 = 0.f, s2 = 0.f;
  float s3[D] = {0.f, 0.f, 0.f, 0.f, 0.f, 0.f, 0.f, 0.f};
  float s4[2][D];
#pragma unroll
  for (int t = 0; t < 2; ++t)
#pragma unroll
    for (int m = 0; m < D; ++m) s4[t][m] = 0.f;

#pragma unroll 1
  for (int t = 0; t < MSTEP; ++t) {
    int rc = t + 1;
    rc = rc < nrows ? rc : nrows - 1;  // clamp -> zero-increment pad
    float nm[D];
    *(float4*)&nm[0] = *(const float4*)&lp[rc * D];
    *(float4*)&nm[4] = *(const float4*)&lp[rc * D + 4];
    float nwi = lp[rc * D + i];
    float nwj = lp[rc * D + j];

    float wm[D];
#pragma unroll
    for (int m = 0; m < D; ++m) wm[m] = nm[m] - cm[m];
    float wi = nwi - cwi, wj = nwj - cwj;

    // level-4 slice: S4 += S3(x)w + S2(x)w^2/2 + S1(x)w^3/6 + w^4/24 (Horner)
    float h1  = __builtin_fmaf(wi, 0.25f, s1);
    float h2  = __builtin_fmaf(h1, wj * (1.f / 3.f), s2);
    float hb2 = h2 * 0.5f;
    float b3a = __builtin_fmaf(hb2, wm[k0], s3[k0]);
    float b3b = __builtin_fmaf(hb2, wm[k0 + 1], s3[k0 + 1]);
#pragma unroll
    for (int m = 0; m < D; ++m) s4[0][m] = __builtin_fmaf(b3a, wm[m], s4[0][m]);
#pragma unroll
    for (int m = 0; m < D; ++m) s4[1][m] = __builtin_fmaf(b3b, wm[m], s4[1][m]);

    // level 3 (full, replicated across q-waves)
    float c1 = __builtin_fmaf(wi, (1.f / 3.f), s1);
    float c2 = __builtin_fmaf(c1, wj * 0.5f, s2);
#pragma unroll
    for (int k = 0; k < D; ++k) s3[k] = __builtin_fmaf(c2, wm[k], s3[k]);

    // levels 2, 1
    float d1 = __builtin_fmaf(wi, 0.5f, s1);
    s2 = __builtin_fmaf(d1, wj, s2);
    s1 += wi;

#pragma unroll
    for (int m = 0; m < D; ++m) cm[m] = nm[m];
    cwi = nwi; cwj = nwj;
  }

  float* __restrict__ slot = ws + (size_t)(b * CHUNKS + c) * SIG_STRIDE;
  store8(slot + OFF4 + lane * 64 + k0 * 8, s4[0]);
  store8(slot + OFF4 + lane * 64 + (k0 + 1) * 8, s4[1]);
  if (q == 0) {
    if (j == 0) slot[i] = s1;
    slot[OFF2 + lane] = s2;
    store8(slot + OFF3 + lane * 8, s3);
  }
}

// Full-state Chen fold: state (s1,s2,s3[8],s4[8][8]) x= B, where B's levels
// 1-3 are in LDS at L13 (584 floats, raw layout) and B's S4 is in global at
// gB4 (lane-private 256B contiguous). Lane (i,j) owns S*[i][j]...
__device__ __forceinline__ void fold_full(float& s1, float& s2, float s3[D],
                                          float s4[D][D],
                                          const float* __restrict__ L13,
                                          const float* __restrict__ gB4,
                                          int i, int j, int lane) {
  float b4[D][D];
#pragma unroll
  for (int k = 0; k < D; ++k) load8(gB4 + lane * 64 + k * 8, b4[k]);

  float b1i = L13[i];
  float b1j = L13[j];
  float sb1[D];
#pragma unroll
  for (int m = 0; m < D; ++m) sb1[m] = L13[m];
  float b2own = L13[OFF2 + lane];
  float b2row[D], b3own[D];
  *(float4*)&b2row[0] = *(const float4*)&L13[OFF2 + j * 8];
  *(float4*)&b2row[4] = *(const float4*)&L13[OFF2 + j * 8 + 4];
  *(float4*)&b3own[0] = *(const float4*)&L13[OFF3 + lane * 8];
  *(float4*)&b3own[4] = *(const float4*)&L13[OFF3 + lane * 8 + 4];

  // C4[i,j,k,m] = A4 + B4 + A3[i,j,k]B1[m] + A2[i,j]B2[k,m] + A1[i]B3[j,k,m]
#pragma unroll
  for (int k = 0; k < D; ++k) {
    float b2k[D], b3k[D];
    *(float4*)&b2k[0] = *(const float4*)&L13[OFF2 + k * 8];
    *(float4*)&b2k[4] = *(const float4*)&L13[OFF2 + k * 8 + 4];
    *(float4*)&b3k[0] = *(const float4*)&L13[OFF3 + (j * 8 + k) * 8];
    *(float4*)&b3k[4] = *(const float4*)&L13[OFF3 + (j * 8 + k) * 8 + 4];
    float a3k = s3[k];
#pragma unroll
    for (int m = 0; m < D; ++m) {
      float v = __builtin_fmaf(a3k, sb1[m], s4[k][m] + b4[k][m]);
      v = __builtin_fmaf(s2, b2k[m], v);
      s4[k][m] = __builtin_fmaf(s1, b3k[m], v);
    }
  }
  // C3[i,j,k] = A3 + B3 + A1[i]B2[j,k] + A2[i,j]B1[k]
#pragma unroll
  for (int k = 0; k < D; ++k) {
    float v = __builtin_fmaf(s1, b2row[k], s3[k] + b3own[k]);
    s3[k] = __builtin_fmaf(s2, sb1[k], v);
  }
  s2 = s2 + b2own + s1 * b1j;
  s1 = s1 + b1i;
}

// ------ Kernel 2: one block per batch; 5-round binary Chen tree -------------
__global__ __launch_bounds__(512, 1) void sig_foldtree(float* __restrict__ ws,
                                                       float* __restrict__ out) {
  __shared__ alignas(16) float L[CHUNKS * L13F];  // 74.75 KB

  const int tid  = threadIdx.x;
  const int wv   = tid >> 6;   // wave 0..7
  const int lane = tid & 63;
  const int i = lane >> 3;
  const int j = lane & 7;
  const int bb = blockIdx.x;
  float* __restrict__ base = ws + (size_t)bb * CHUNKS * SIG_STRIDE;

  // Stage levels 1-3 of all 32 sigs into LDS (coalesced float4).
  for (int n = tid; n < CHUNKS * L13F4; n += 512) {
    unsigned s = (unsigned)n / L13F4;
    unsigned o = (unsigned)n - s * L13F4;
    *(float4*)&L[s * L13F + o * 4] =
        *(const float4*)(base + (size_t)s * SIG_STRIDE + o * 4);
  }
  __syncthreads();

  // Rounds r=0..4: pairs (a, a+2^r) -> a, stride-2^(r+1) slots.
#pragma unroll 1
  for (int r = 0; r < 5; ++r) {
    const int npairs = 16 >> r;
#pragma unroll 1
    for (int p = wv; p < npairs; p += 8) {
      const int a   = p * (2 << r);
      const int bsl = a + (1 << r);
      float* __restrict__ A13 = &L[a * L13F];
      float* __restrict__ gA4 = base + (size_t)a * SIG_STRIDE + OFF4;

      // load A state
      float s1 = A13[i];
      float s2 = A13[OFF2 + lane];
      float s3[D], s4[D][D];
      *(float4*)&s3[0] = *(const float4*)&A13[OFF3 + lane * 8];
      *(float4*)&s3[4] = *(const float4*)&A13[OFF3 + lane * 8 + 4];
#pragma unroll
      for (int k = 0; k < D; ++k) load8(gA4 + lane * 64 + k * 8, s4[k]);

      fold_full(s1, s2, s3, s4, &L[bsl * L13F],
                base + (size_t)bsl * SIG_STRIDE + OFF4, i, j, lane);

      if (r < 4) {
        // write back into slot a (levels 1-3 -> LDS, S4 -> global/L2)
        if (j == 0) A13[i] = s1;
        A13[OFF2 + lane] = s2;
        *(float4*)&A13[OFF3 + lane * 8]     = make_float4(s3[0], s3[1], s3[2], s3[3]);
        *(float4*)&A13[OFF3 + lane * 8 + 4] = make_float4(s3[4], s3[5], s3[6], s3[7]);
#pragma unroll
        for (int k = 0; k < D; ++k) store8(gA4 + lane * 64 + k * 8, s4[k]);
      } else {
        // final result -> d_out: S1 (32x8) | S2 (32x64) | S3 (32x512) | S4 (32x4096)
        if (j == 0) out[bb * 8 + i] = s1;
        out[256 + bb * 64 + lane] = s2;
        store8(out + 2304 + bb * 512 + lane * 8, s3);
#pragma unroll
        for (int k = 0; k < D; ++k)
          store8(out + 18688 + bb * 4096 + lane * 64 + k * 8, s4[k]);
      }
    }
    __syncthreads();
  }
}

extern "C" void kernel_launch(void* const* d_in, const int* in_sizes, int n_in,
                              void* d_out, int out_size, void* d_ws, size_t ws_size,
                              hipStream_t stream) {
  const float* path = (const float*)d_in[0];
  // d_in[1] = depth (==4), compile-time specialized.
  float* out = (float*)d_out;
  float* ws  = (float*)d_ws;  // 32*32*4680*4 = 19.2 MB used

  // one block per chunk: 32 batches x 32 chunks = 1024 blocks (4 q-waves)
  sig_chunk<<<dim3(1024), dim3(256), 0, stream>>>(path, ws);
  // one block per batch: 32 blocks x 8 waves; in-block binary Chen tree
  sig_foldtree<<<dim3(BATCH), dim3(512), 0, stream>>>(ws, out);
}